// Round 11
// baseline (54.666 us; speedup 1.0000x reference)
//
#include <hip/hip_runtime.h>
#include <hip/hip_bf16.h>

typedef __attribute__((ext_vector_type(4))) int i32x4;
typedef __attribute__((ext_vector_type(8))) int i32x8;
typedef __attribute__((ext_vector_type(16))) float f32x16;

#define AS1 __attribute__((address_space(1)))
#define AS3 __attribute__((address_space(3)))

#define DDIM 512
#define RB 256   // row bytes of fp4 z (512 elements * 0.5 B)

// ---- fp4 e2m1 encode: nearest value in ±{0,0.5,1,1.5,2,3,4,6} ----
__device__ inline unsigned enc_fp4(float x) {
  const unsigned s = (__float_as_uint(x) >> 31) << 3;
  const float y = fabsf(x);
  unsigned m;
  if (y < 1.75f)      m = (unsigned)rintf(y * 2.0f);       // 0,0.5,1,1.5
  else if (y < 3.5f)  m = 4u + (unsigned)rintf(y - 2.0f);  // 2,3
  else                m = (y >= 5.0f) ? 7u : 6u;           // 4,6 (clamp)
  return s | m;
}

// ---------------- Kernel 1: normalize + pos-pair dot + fp4 write ----------------
// zq[row] = fp4(32 * z_hat[row]), 2 elements/byte (elem 2t low nibble).
__global__ __launch_bounds__(256) void norm_pd_kernel(
    const float* __restrict__ ei, const float* __restrict__ ej,
    unsigned char* __restrict__ zq, float* __restrict__ pd,
    float* __restrict__ rowsum, float* __restrict__ out, int N) {
  const int k = blockIdx.x;
  const int t = threadIdx.x;
  const float2 a = *reinterpret_cast<const float2*>(ei + (size_t)k * DDIM + t * 2);
  const float2 b = *reinterpret_cast<const float2*>(ej + (size_t)k * DDIM + t * 2);
  float sii = a.x * a.x + a.y * a.y;
  float sjj = b.x * b.x + b.y * b.y;
  float sij = a.x * b.x + a.y * b.y;
#pragma unroll
  for (int off = 32; off; off >>= 1) {
    sii += __shfl_down(sii, off);
    sjj += __shfl_down(sjj, off);
    sij += __shfl_down(sij, off);
  }
  __shared__ float red[3][4];
  if ((t & 63) == 0) { red[0][t >> 6] = sii; red[1][t >> 6] = sjj; red[2][t >> 6] = sij; }
  __syncthreads();
  sii = red[0][0] + red[0][1] + red[0][2] + red[0][3];
  sjj = red[1][0] + red[1][1] + red[1][2] + red[1][3];
  sij = red[2][0] + red[2][1] + red[2][2] + red[2][3];
  const float rsi = rsqrtf(sii), rsj = rsqrtf(sjj);

  const float sa0 = 32.0f * a.x * rsi, sa1 = 32.0f * a.y * rsi;
  const float sb0 = 32.0f * b.x * rsj, sb1 = 32.0f * b.y * rsj;
  const unsigned char ba = (unsigned char)(enc_fp4(sa0) | (enc_fp4(sa1) << 4));
  const unsigned char bb = (unsigned char)(enc_fp4(sb0) | (enc_fp4(sb1) << 4));
  zq[(size_t)k * RB + t] = ba;
  zq[(size_t)(N + k) * RB + t] = bb;
  if (t == 0) {
    pd[k] = sij * rsi * rsj;
    rowsum[k] = 0.0f;
    rowsum[N + k] = 0.0f;
    if (k == 0) out[0] = 0.0f;
  }
}

// ---------------- Kernel 2: MX-fp4 32x32x64 fused sim-GEMM ---------------------
// 128x128 tile, 4 waves (64x64/wave, 2x2 frags of 32x32). K-tile = 128 elems
// (64 B/row). LDS half = [4 chunks][128 rows][16 B] (k-major subtiles) ->
// frag ds_read_b128 is CONTIGUOUS per 32-lane half = conflict-free, and the
// layout matches global_load_lds's forced linear dest (rule #21).
// Double-buffer, counted vmcnt(4), raw barriers, no sched fences (m141).
// Scales: all bytes 0x7F (=1.0) -> scale semantics neutral; hi 4 operand regs
// zeroed; any k-permutation inside the MFMA cancels (same map for A and B).

__global__ __launch_bounds__(256, 4) void simloss_main(
    const unsigned char* __restrict__ zq, float* __restrict__ rowsum, int nwg) {
  // ---- bijective XCD-chunk remap (nwg = 2080 = 8*260, r8 = 0) ----
  const int orig = blockIdx.x;
  const int q = nwg >> 3, r8 = nwg & 7;
  const int xcd = orig & 7, pos0 = orig >> 3;
  const int t0 = (xcd < r8 ? xcd * (q + 1) : r8 * (q + 1) + (xcd - r8) * q) + pos0;

  // ---- triangular decode: t0 -> (bx, by), bx <= by ----
  const float ff = sqrtf(8.0f * (float)t0 + 1.0f);
  int by = (int)((ff - 1.0f) * 0.5f);
  while ((by + 1) * (by + 2) / 2 <= t0) ++by;
  while (by * (by + 1) / 2 > t0) --by;
  const int bx = t0 - by * (by + 1) / 2;

  const int row0 = bx * 128;
  const int col0 = by * 128;

  __shared__ __align__(16) unsigned char lds[2][2][8192];  // [buf][A,B][4x128x16]

  const int tid = threadIdx.x;
  const int w = tid >> 6;          // wave 0..3
  const int l = tid & 63;
  const int trw = (w >> 1) * 64;   // wave row offset in tile
  const int tcw = (w & 1) * 64;    // wave col offset in tile
  const int lh = l >> 5;           // lane k-half
  const int l31 = l & 31;

  f32x16 acc[2][2] = {};

  // stage one K-tile (A+B panels) into buffer buf. 4 loads/thread.
  auto stage = [&](int buf, int t) {
    const int kb = t * 64;  // byte offset of this K-tile within a row
#pragma unroll
    for (int half = 0; half < 2; ++half) {
      const int baserow = half ? col0 : row0;
#pragma unroll
      for (int it = 0; it < 2; ++it) {
        const int idx = it * 256 + tid;      // 16B chunk id 0..511
        const int r = idx & 127;             // panel row
        const int c = idx >> 7;              // k-chunk 0..3
        const unsigned char* src = zq + (size_t)(baserow + r) * RB + kb + c * 16;
        char* dst = (char*)&lds[buf][half][0] + (unsigned)((it * 256 + w * 64) * 16);
        __builtin_amdgcn_global_load_lds((const AS1 void*)src, (AS3 void*)dst, 16, 0, 0);
      }
    }
  };

  auto compute = [&](int buf) {
    const unsigned char* ab = &lds[buf][0][0];
    const unsigned char* bb = &lds[buf][1][0];
    i32x4 A4[2][2], B4[2][2];  // [mf|nf][kk]
#pragma unroll
    for (int mf = 0; mf < 2; ++mf)
#pragma unroll
      for (int kk = 0; kk < 2; ++kk) {
        const int cch = kk * 2 + lh;
        A4[mf][kk] = *reinterpret_cast<const i32x4*>(ab + cch * 2048 + (trw + mf * 32 + l31) * 16);
        B4[mf][kk] = *reinterpret_cast<const i32x4*>(bb + cch * 2048 + (tcw + mf * 32 + l31) * 16);
      }
#pragma unroll
    for (int mf = 0; mf < 2; ++mf)
#pragma unroll
      for (int nf = 0; nf < 2; ++nf)
#pragma unroll
        for (int kk = 0; kk < 2; ++kk) {
          const i32x8 a8 = {A4[mf][kk].x, A4[mf][kk].y, A4[mf][kk].z, A4[mf][kk].w, 0, 0, 0, 0};
          const i32x8 b8 = {B4[nf][kk].x, B4[nf][kk].y, B4[nf][kk].z, B4[nf][kk].w, 0, 0, 0, 0};
          acc[mf][nf] = __builtin_amdgcn_mfma_scale_f32_32x32x64_f8f6f4(
              a8, b8, acc[mf][nf], 4, 4,  // cbsz=fp4(A), blgp=fp4(B)
              0, 0x7f7f7f7f,              // A scale opsel, scale bytes = 1.0
              0, 0x7f7f7f7f);             // B scale
        }
  };

  // ---- prologue + K-loop: 4 tiles of K=128 ----
  stage(0, 0);
#pragma unroll
  for (int t = 0; t < 3; ++t) {
    stage((t & 1) ^ 1, t + 1);
    asm volatile("s_waitcnt vmcnt(4)" ::: "memory");  // tile t's 4 loads landed
    __builtin_amdgcn_s_barrier();
    compute(t & 1);
    __builtin_amdgcn_s_barrier();
  }
  asm volatile("s_waitcnt vmcnt(0)" ::: "memory");
  __builtin_amdgcn_s_barrier();
  compute(1);

  // ---- epilogue ----
  // 32x32 C/D layout: col = l&31, row = (rg&3) + 8*(rg>>2) + 4*(l>>5)
  const float SC = 2.0f * 1.44269504088896340736f / 1024.0f;  // 2*log2e/(32*32)

#pragma unroll
  for (int mf = 0; mf < 2; ++mf)
#pragma unroll
    for (int nf = 0; nf < 2; ++nf)
#pragma unroll
      for (int rg = 0; rg < 16; ++rg)
        acc[mf][nf][rg] = exp2f(acc[mf][nf][rg] * SC);

  // row sums: reduce over this wave's 64 cols (nf pair + 32 lanes of the half)
#pragma unroll
  for (int mf = 0; mf < 2; ++mf) {
    float rs[16];
#pragma unroll
    for (int rg = 0; rg < 16; ++rg) rs[rg] = acc[mf][0][rg] + acc[mf][1][rg];
#pragma unroll
    for (int off = 1; off < 32; off <<= 1) {
#pragma unroll
      for (int rg = 0; rg < 16; ++rg) rs[rg] += __shfl_xor(rs[rg], off);
    }
    if (l31 == 0) {  // lanes 0 and 32 (different row sets via lh)
#pragma unroll
      for (int rg = 0; rg < 16; ++rg) {
        const int row = row0 + trw + mf * 32 + (rg & 3) + 8 * (rg >> 2) + 4 * lh;
        atomicAdd(&rowsum[row], rs[rg]);
      }
    }
  }

  // column sums (mirror) — off-diagonal tiles only
  if (bx != by) {
#pragma unroll
    for (int nf = 0; nf < 2; ++nf) {
      float cs = 0.0f;
#pragma unroll
      for (int mf = 0; mf < 2; ++mf)
#pragma unroll
        for (int rg = 0; rg < 16; ++rg) cs += acc[mf][nf][rg];
      cs += __shfl_xor(cs, 32);  // combine the two row-half partials
      if (l < 32) atomicAdd(&rowsum[col0 + tcw + nf * 32 + l], cs);
    }
  }
}

// ---------------- Kernel 3: finalize (parallel, atomic partials) ----------------
__global__ __launch_bounds__(1024) void finalize_kernel(
    const float* __restrict__ rowsum, const float* __restrict__ pd,
    float* __restrict__ out, int M, int N) {
  const int i = blockIdx.x * 1024 + threadIdx.x;
  const float E2 = 7.38905609893065f;  // exp(2) — reference diagonal (unit rows)
  float acc = 0.0f;
  if (i < M) {
    const float denom = rowsum[i] - E2;
    const int kk = (i < N) ? i : (i - N);
    acc = logf(denom) - 2.0f * pd[kk];
  }
#pragma unroll
  for (int off = 32; off; off >>= 1) acc += __shfl_down(acc, off);
  __shared__ float red[16];
  const int t = threadIdx.x;
  if ((t & 63) == 0) red[t >> 6] = acc;
  __syncthreads();
  if (t < 64) {
    float s = (t < 16) ? red[t] : 0.0f;
#pragma unroll
    for (int off = 8; off; off >>= 1) s += __shfl_down(s, off);
    if (t == 0) atomicAdd(out, s / (float)M);
  }
}

extern "C" void kernel_launch(void* const* d_in, const int* in_sizes, int n_in,
                              void* d_out, int out_size, void* d_ws, size_t ws_size,
                              hipStream_t stream) {
  const float* ei = (const float*)d_in[0];
  const float* ej = (const float*)d_in[1];
  float* out = (float*)d_out;

  const int N = in_sizes[0] / DDIM;  // 4096
  const int M = 2 * N;               // 8192
  const int NT = M / 128;            // 64 tiles per dim
  const int NTRI = NT * (NT + 1) / 2;  // 2080 blocks (= 8*260)

  char* ws = (char*)d_ws;
  unsigned char* zq = (unsigned char*)ws;                       // M * 256 B fp4
  float* pd = (float*)(ws + (size_t)M * RB);                    // N f32
  float* rowsum = (float*)(ws + (size_t)M * RB + (size_t)N * 4);  // M f32

  norm_pd_kernel<<<N, 256, 0, stream>>>(ei, ej, zq, pd, rowsum, out, N);
  simloss_main<<<NTRI, 256, 0, stream>>>(zq, rowsum, NTRI);
  finalize_kernel<<<(M + 1023) / 1024, 1024, 0, stream>>>(rowsum, pd, out, M, N);
}

// Round 12
// 48.081 us; speedup vs baseline: 1.1370x; 1.1370x over previous
//
#include <hip/hip_runtime.h>
#include <hip/hip_bf16.h>

typedef __attribute__((ext_vector_type(4))) int i32x4;

#define AS1 __attribute__((address_space(1)))
#define AS3 __attribute__((address_space(3)))

#define DDIM 512
#define BK 64

// ---------------- Kernel 1: normalize + pos-pair dot + int8 write ----------------
__global__ __launch_bounds__(256) void norm_pd_kernel(
    const float* __restrict__ ei, const float* __restrict__ ej,
    unsigned char* __restrict__ zq, float* __restrict__ pd,
    float* __restrict__ rowsum, float* __restrict__ out, int N) {
  const int k = blockIdx.x;
  const int t = threadIdx.x;
  const float2 a = *reinterpret_cast<const float2*>(ei + (size_t)k * DDIM + t * 2);
  const float2 b = *reinterpret_cast<const float2*>(ej + (size_t)k * DDIM + t * 2);
  float sii = a.x * a.x + a.y * a.y;
  float sjj = b.x * b.x + b.y * b.y;
  float sij = a.x * b.x + a.y * b.y;
#pragma unroll
  for (int off = 32; off; off >>= 1) {
    sii += __shfl_down(sii, off);
    sjj += __shfl_down(sjj, off);
    sij += __shfl_down(sij, off);
  }
  __shared__ float red[3][4];
  if ((t & 63) == 0) { red[0][t >> 6] = sii; red[1][t >> 6] = sjj; red[2][t >> 6] = sij; }
  __syncthreads();
  sii = red[0][0] + red[0][1] + red[0][2] + red[0][3];
  sjj = red[1][0] + red[1][1] + red[1][2] + red[1][3];
  sij = red[2][0] + red[2][1] + red[2][2] + red[2][3];
  const float rsi = rsqrtf(sii), rsj = rsqrtf(sjj);

  const int qa0 = (int)rintf(127.0f * a.x * rsi);
  const int qa1 = (int)rintf(127.0f * a.y * rsi);
  const int qb0 = (int)rintf(127.0f * b.x * rsj);
  const int qb1 = (int)rintf(127.0f * b.y * rsj);
  const unsigned short wa = (unsigned short)(qa0 & 0xff) | ((unsigned short)(qa1 & 0xff) << 8);
  const unsigned short wb = (unsigned short)(qb0 & 0xff) | ((unsigned short)(qb1 & 0xff) << 8);
  *reinterpret_cast<unsigned short*>(zq + (size_t)k * DDIM + t * 2) = wa;
  *reinterpret_cast<unsigned short*>(zq + (size_t)(N + k) * DDIM + t * 2) = wb;
  if (t == 0) {
    pd[k] = sij * rsi * rsj;
    rowsum[k] = 0.0f;
    rowsum[N + k] = 0.0f;
    if (k == 0) out[0] = 0.0f;
  }
}

// ---------------- Kernel 2: persistent-block int8 MFMA fused sim-GEMM ----------
// Grid = 1024 blocks (4/CU exactly), each owns 2-3 CONTIGUOUS triangular tiles
// (same-by runs share the B panel in L2). Flat slab pipeline: stage slab s+1
// (possibly next tile's slab 0) BEFORE slab s's trailing barrier, so the
// per-tile epilogue overlaps the next tile's first staging — no per-tile
// prologue, no dispatch rounds/tail. Iteration = R9's proven
// {stage; vmcnt(4); bar; compute; bar}, no sched fences (m141).
// LDS chunk swizzle s=(g+(row>>1))&3 on pre-swizzled global source + ds_read.

#define MFMAI8(A, B, C) __builtin_amdgcn_mfma_i32_16x16x64_i8((A), (B), (C), 0, 0, 0)

__global__ __launch_bounds__(256, 4) void simloss_main(
    const unsigned char* __restrict__ zq, float* __restrict__ rowsum,
    int ntri, int nblk) {
  // ---- per-XCD contiguous tile ranges ----
  const int orig = blockIdx.x;
  const int xcd = orig & 7, p = orig >> 3;
  const int per_xcd = ntri >> 3;          // 260
  const int bpx = nblk >> 3;              // 128
  const int q = per_xcd / bpx, r = per_xcd % bpx;
  const int start = p * q + (p < r ? p : r);
  const int cnt = q + (p < r ? 1 : 0);
  const int tbeg = xcd * per_xcd + start;
  const int tend = tbeg + cnt;

  __shared__ unsigned char lds[2][2][8192];  // [buf][A,B][128 rows x 64 B]

  const int tid = threadIdx.x;
  const int w = tid >> 6;        // wave 0..3
  const int l = tid & 63;
  const int wr = (w >> 1) * 64;  // wave row offset in tile
  const int wc = (w & 1) * 64;   // wave col offset in tile
  const int lrow = l & 15;
  const int g = l >> 4;          // lane chunk-group (16B of k)

  // triangular decode t -> (bx, by)
  auto decode = [&](int t, int& bx, int& by) {
    const float ff = sqrtf(8.0f * (float)t + 1.0f);
    by = (int)((ff - 1.0f) * 0.5f);
    while ((by + 1) * (by + 2) / 2 <= t) ++by;
    while (by * (by + 1) / 2 > t) --by;
    bx = t - by * (by + 1) / 2;
  };

  // stage one K-slab (A+B panels, 4 loads/thread) into lds[buf]
  auto stage = [&](int buf, int arow, int brow, int k0) {
#pragma unroll
    for (int half = 0; half < 2; ++half) {
      const int baserow = half ? brow : arow;
#pragma unroll
      for (int it = 0; it < 2; ++it) {
        const int pp = it * 256 + tid;        // 16B chunk id 0..511
        const int row = pp >> 2;              // 0..127
        const int s = pp & 3;                 // stored chunk slot
        const int gs = (s - (row >> 1)) & 3;  // source chunk (swizzle inverse)
        const unsigned char* src = zq + (size_t)(baserow + row) * DDIM + k0 + gs * 16;
        char* dst = (char*)&lds[buf][half][0] + (unsigned)((it * 256 + w * 64) * 16);
        __builtin_amdgcn_global_load_lds((const AS1 void*)src, (AS3 void*)dst, 16, 0, 0);
      }
    }
  };

  i32x4 acc[4][4] = {};

  auto compute = [&](int buf) {
    const unsigned char* ab = &lds[buf][0][0];
    const unsigned char* bb = &lds[buf][1][0];
    i32x4 Af[4], Bf[4];
#pragma unroll
    for (int mf = 0; mf < 4; ++mf) {
      const int rr = wr + mf * 16 + lrow;
      Af[mf] = *reinterpret_cast<const i32x4*>(ab + rr * 64 + (((g + (rr >> 1)) & 3) << 4));
    }
#pragma unroll
    for (int nf = 0; nf < 4; ++nf) {
      const int cc = wc + nf * 16 + lrow;
      Bf[nf] = *reinterpret_cast<const i32x4*>(bb + cc * 64 + (((g + (cc >> 1)) & 3) << 4));
    }
#pragma unroll
    for (int mf = 0; mf < 4; ++mf)
#pragma unroll
      for (int nf = 0; nf < 4; ++nf)
        acc[mf][nf] = MFMAI8(Af[mf], Bf[nf], acc[mf][nf]);
  };

  const float SC = 2.0f * 1.44269504088896340736f / 16129.0f;  // 2*log2(e)/127^2
  const int lgrp = l >> 4;
  const int lcol = l & 15;

  if (tbeg >= tend) return;

  int bx, by;
  decode(tbeg, bx, by);
  int row0 = bx * 128, col0 = by * 128;
  int nbx, nby, nrow0 = 0, ncol0 = 0;

  stage(0, row0, col0, 0);  // first slab of first tile
  int buf = 0;

  for (int ti = tbeg; ti < tend; ++ti) {
    const bool havenext = (ti + 1 < tend);
    if (havenext) {
      decode(ti + 1, nbx, nby);
      nrow0 = nbx * 128; ncol0 = nby * 128;
    }
#pragma unroll
    for (int t = 0; t < 8; ++t) {
      if (t < 7) {
        stage(buf ^ 1, row0, col0, (t + 1) * BK);
        asm volatile("s_waitcnt vmcnt(4)" ::: "memory");
      } else if (havenext) {
        stage(buf ^ 1, nrow0, ncol0, 0);
        asm volatile("s_waitcnt vmcnt(4)" ::: "memory");
      } else {
        asm volatile("s_waitcnt vmcnt(0)" ::: "memory");
      }
      __builtin_amdgcn_s_barrier();
      compute(buf);
      __builtin_amdgcn_s_barrier();
      buf ^= 1;
    }

    // ---- epilogue for tile ti (overlaps next tile's slab-0 staging) ----
    float e[4][4][4];
#pragma unroll
    for (int mf = 0; mf < 4; ++mf)
#pragma unroll
      for (int nf = 0; nf < 4; ++nf)
#pragma unroll
        for (int rg = 0; rg < 4; ++rg)
          e[mf][nf][rg] = exp2f((float)acc[mf][nf][rg] * SC);

#pragma unroll
    for (int mf = 0; mf < 4; ++mf) {
      float rs[4];
#pragma unroll
      for (int rg = 0; rg < 4; ++rg) {
        float s = 0.0f;
#pragma unroll
        for (int nf = 0; nf < 4; ++nf) s += e[mf][nf][rg];
        rs[rg] = s;
      }
#pragma unroll
      for (int off = 1; off < 16; off <<= 1) {
#pragma unroll
        for (int rg = 0; rg < 4; ++rg) rs[rg] += __shfl_xor(rs[rg], off);
      }
      if (lcol == 0) {
        const int rowb = row0 + wr + mf * 16 + lgrp * 4;
#pragma unroll
        for (int rg = 0; rg < 4; ++rg) atomicAdd(&rowsum[rowb + rg], rs[rg]);
      }
    }

    if (bx != by) {
#pragma unroll
      for (int nf = 0; nf < 4; ++nf) {
        float cs = 0.0f;
#pragma unroll
        for (int mf = 0; mf < 4; ++mf)
#pragma unroll
          for (int rg = 0; rg < 4; ++rg) cs += e[mf][nf][rg];
        cs += __shfl_xor(cs, 16);
        cs += __shfl_xor(cs, 32);
        if (lgrp == 0) atomicAdd(&rowsum[col0 + wc + nf * 16 + lcol], cs);
      }
    }

    // reset for next tile
#pragma unroll
    for (int mf = 0; mf < 4; ++mf)
#pragma unroll
      for (int nf = 0; nf < 4; ++nf)
        acc[mf][nf] = i32x4{0, 0, 0, 0};
    bx = nbx; by = nby; row0 = nrow0; col0 = ncol0;
  }
}

// ---------------- Kernel 3: finalize (parallel, atomic partials) ----------------
__global__ __launch_bounds__(1024) void finalize_kernel(
    const float* __restrict__ rowsum, const float* __restrict__ pd,
    float* __restrict__ out, int M, int N) {
  const int i = blockIdx.x * 1024 + threadIdx.x;
  const float E2 = 7.38905609893065f;  // exp(2) — diagonal term (unit rows)
  float acc = 0.0f;
  if (i < M) {
    const float denom = rowsum[i] - E2;
    const int kk = (i < N) ? i : (i - N);
    acc = logf(denom) - 2.0f * pd[kk];
  }
#pragma unroll
  for (int off = 32; off; off >>= 1) acc += __shfl_down(acc, off);
  __shared__ float red[16];
  const int t = threadIdx.x;
  if ((t & 63) == 0) red[t >> 6] = acc;
  __syncthreads();
  if (t < 64) {
    float s = (t < 16) ? red[t] : 0.0f;
#pragma unroll
    for (int off = 8; off; off >>= 1) s += __shfl_down(s, off);
    if (t == 0) atomicAdd(out, s / (float)M);
  }
}

extern "C" void kernel_launch(void* const* d_in, const int* in_sizes, int n_in,
                              void* d_out, int out_size, void* d_ws, size_t ws_size,
                              hipStream_t stream) {
  const float* ei = (const float*)d_in[0];
  const float* ej = (const float*)d_in[1];
  float* out = (float*)d_out;

  const int N = in_sizes[0] / DDIM;  // 4096
  const int M = 2 * N;               // 8192
  const int NT = M / 128;            // 64 tiles per dim
  const int NTRI = NT * (NT + 1) / 2;  // 2080 tiles (= 8*260)
  const int NBLK = 1024;             // persistent: 4 blocks/CU

  char* ws = (char*)d_ws;
  unsigned char* zq = (unsigned char*)ws;                        // M * 512 i8
  float* pd = (float*)(ws + (size_t)M * DDIM);                   // N f32
  float* rowsum = (float*)(ws + (size_t)M * DDIM + (size_t)N * 4);  // M f32

  norm_pd_kernel<<<N, 256, 0, stream>>>(ei, ej, zq, pd, rowsum, out, N);
  simloss_main<<<NBLK, 256, 0, stream>>>(zq, rowsum, NTRI, NBLK);
  finalize_kernel<<<(M + 1023) / 1024, 1024, 0, stream>>>(rowsum, pd, out, M, N);
}